// Round 1
// baseline (8434.615 us; speedup 1.0000x reference)
//
#include <hip/hip_runtime.h>
#include <cstddef>

#define TSTEPS 365
#define NGRID_ 2000
#define NX_ 16
#define H_ 256
#define CPB 8                 // grid cells per block
#define NBLK (NGRID_ / CPB)   // 250 blocks

__device__ __forceinline__ float sigmoid_f(float v) {
    return 1.0f / (1.0f + __expf(-v));
}
// tanh via exp: handles saturation correctly (inf -> +/-1)
__device__ __forceinline__ float tanh_f(float v) {
    return 1.0f - 2.0f / (__expf(2.0f * v) + 1.0f);
}

__global__ __launch_bounds__(H_) void lstm_fused(
    const float* __restrict__ x,     // [T][NGRID][NX]
    const float* __restrict__ wx,    // [4][NX][H]
    const float* __restrict__ wh,    // [4][H][H]
    const float* __restrict__ b,     // [4][H]
    const float* __restrict__ wlin,  // [H]
    const float* __restrict__ blin,  // [1]
    float* __restrict__ out)         // [T][NGRID]
{
    __shared__ float h_sh[H_][CPB];   // [k][n]  -> per-k broadcast reads as 2x float4
    __shared__ float x_sh[NX_][CPB];  // [i][n]
    __shared__ float red[4][CPB];     // per-wave output partials

    const int j    = threadIdx.x;       // hidden unit 0..255
    const int c0   = blockIdx.x * CPB;  // first grid cell of this block
    const int wave = j >> 6;
    const int lane = j & 63;

    // persistent per-thread constants
    const float bias0 = b[0 * H_ + j];
    const float bias1 = b[1 * H_ + j];
    const float bias2 = b[2 * H_ + j];
    const float bias3 = b[3 * H_ + j];
    const float wl = wlin[j];
    const float bl = blin[0];

    float c_reg[CPB];
#pragma unroll
    for (int n = 0; n < CPB; ++n) c_reg[n] = 0.0f;

    // h(0) = 0
#pragma unroll
    for (int n = 0; n < CPB; ++n) h_sh[j][n] = 0.0f;
    // stage x for t = 0
    if (j < NX_ * CPB) {
        const int n = j >> 4, i = j & 15;
        x_sh[i][n] = x[(size_t)(c0 + n) * NX_ + i];
    }
    __syncthreads();

    for (int t = 0; t < TSTEPS; ++t) {
        // gate pre-activation accumulators: acc[n][g]
        float acc[CPB][4];
#pragma unroll
        for (int n = 0; n < CPB; ++n) {
            acc[n][0] = bias0; acc[n][1] = bias1;
            acc[n][2] = bias2; acc[n][3] = bias3;
        }

        // input projection: xg = x_t @ wx  (16 k-iterations worth of work)
#pragma unroll 4
        for (int i = 0; i < NX_; ++i) {
            const float w0 = wx[0 * NX_ * H_ + i * H_ + j];
            const float w1 = wx[1 * NX_ * H_ + i * H_ + j];
            const float w2 = wx[2 * NX_ * H_ + i * H_ + j];
            const float w3 = wx[3 * NX_ * H_ + i * H_ + j];
            const float4 xv0 = *(const float4*)&x_sh[i][0];
            const float4 xv1 = *(const float4*)&x_sh[i][4];
            const float xv[8] = {xv0.x, xv0.y, xv0.z, xv0.w,
                                 xv1.x, xv1.y, xv1.z, xv1.w};
#pragma unroll
            for (int n = 0; n < CPB; ++n) {
                acc[n][0] = fmaf(xv[n], w0, acc[n][0]);
                acc[n][1] = fmaf(xv[n], w1, acc[n][1]);
                acc[n][2] = fmaf(xv[n], w2, acc[n][2]);
                acc[n][3] = fmaf(xv[n], w3, acc[n][3]);
            }
        }

        // recurrent projection: g += h @ wh
        const float* whb = wh + j;
#pragma unroll 4
        for (int k = 0; k < H_; ++k) {
            const float w0 = whb[0 * H_ * H_ + k * H_];
            const float w1 = whb[1 * H_ * H_ + k * H_];
            const float w2 = whb[2 * H_ * H_ + k * H_];
            const float w3 = whb[3 * H_ * H_ + k * H_];
            const float4 hv0 = *(const float4*)&h_sh[k][0];
            const float4 hv1 = *(const float4*)&h_sh[k][4];
            const float hv[8] = {hv0.x, hv0.y, hv0.z, hv0.w,
                                 hv1.x, hv1.y, hv1.z, hv1.w};
#pragma unroll
            for (int n = 0; n < CPB; ++n) {
                acc[n][0] = fmaf(hv[n], w0, acc[n][0]);
                acc[n][1] = fmaf(hv[n], w1, acc[n][1]);
                acc[n][2] = fmaf(hv[n], w2, acc[n][2]);
                acc[n][3] = fmaf(hv[n], w3, acc[n][3]);
            }
        }

        __syncthreads();  // all lanes done reading h_sh / x_sh of this step

        // gates + state update (c in registers)
        float hnew[CPB];
#pragma unroll
        for (int n = 0; n < CPB; ++n) {
            const float ig = sigmoid_f(acc[n][0]);
            const float fg = sigmoid_f(acc[n][1]);
            const float gt = tanh_f(acc[n][2]);
            const float og = sigmoid_f(acc[n][3]);
            const float c  = fmaf(fg, c_reg[n], ig * gt);
            c_reg[n] = c;
            hnew[n]  = og * tanh_f(c);
        }

        // publish h(t) for next step: thread j owns row j
        *(float4*)&h_sh[j][0] = make_float4(hnew[0], hnew[1], hnew[2], hnew[3]);
        *(float4*)&h_sh[j][4] = make_float4(hnew[4], hnew[5], hnew[6], hnew[7]);

        // output head: out[t][n] = sum_j hnew[n][j]*wlin[j] + blin
#pragma unroll
        for (int n = 0; n < CPB; ++n) {
            float p = hnew[n] * wl;
#pragma unroll
            for (int off = 32; off > 0; off >>= 1) p += __shfl_down(p, off);
            if (lane == 0) red[wave][n] = p;
        }

        // stage x for t+1
        if (t + 1 < TSTEPS && j < NX_ * CPB) {
            const int n = j >> 4, i = j & 15;
            x_sh[i][n] = x[((size_t)(t + 1) * NGRID_ + c0 + n) * NX_ + i];
        }

        __syncthreads();  // h(t), red, x(t+1) visible

        if (j < CPB) {
            out[(size_t)t * NGRID_ + c0 + j] =
                red[0][j] + red[1][j] + red[2][j] + red[3][j] + bl;
        }
    }
}

extern "C" void kernel_launch(void* const* d_in, const int* in_sizes, int n_in,
                              void* d_out, int out_size, void* d_ws, size_t ws_size,
                              hipStream_t stream) {
    const float* x    = (const float*)d_in[0];
    const float* wx   = (const float*)d_in[1];
    const float* wh   = (const float*)d_in[2];
    const float* b    = (const float*)d_in[3];
    const float* wlin = (const float*)d_in[4];
    const float* blin = (const float*)d_in[5];
    float* out = (float*)d_out;

    hipLaunchKernelGGL(lstm_fused, dim3(NBLK), dim3(H_), 0, stream,
                       x, wx, wh, b, wlin, blin, out);
}

// Round 2
// 4877.317 us; speedup vs baseline: 1.7294x; 1.7294x over previous
//
#include <hip/hip_runtime.h>
#include <cstddef>

#define TSTEPS 365
#define NGRID_ 2000
#define NX_ 16
#define H_ 256
#define CPB 16
#define NBLK (NGRID_ / CPB)   // 125 blocks, 512 threads each

typedef __attribute__((ext_vector_type(8))) short short8v;
typedef __attribute__((ext_vector_type(4))) float f32x4;

__device__ __forceinline__ unsigned short f2bf(float f) {
    unsigned int u = __float_as_uint(f);
    u += 0x7fffu + ((u >> 16) & 1u);   // round-to-nearest-even
    return (unsigned short)(u >> 16);
}
__device__ __forceinline__ float bf2f(unsigned short s) {
    return __uint_as_float(((unsigned int)s) << 16);
}
__device__ __forceinline__ float sigmoid_f(float v) {
    return 1.0f / (1.0f + __expf(-v));
}
__device__ __forceinline__ float tanh_f(float v) {
    return 1.0f - 2.0f / (__expf(2.0f * v) + 1.0f);
}

// ---------------------------------------------------------------------------
// Pack wh [4][256][256] and wx [4][16][256] (fp32) into bf16 MFMA B-fragment
// order in d_ws. B-frag for mfma_f32_16x16x32_bf16: lane l holds
// B[k = (l>>4)*8 + j][n = l&15], j=0..7. Chunk index = (gu*8 + kt) for wh
// (gu = g*16 + unit-tile, kt = K-tile of 32), then 64 lanes x 8 bf16 = 1KB.
// wx is packed as one K=32 tile per gu: rows 0..15 = wx, rows 16..31 = wx
// again (A supplies x_hi in k 0..15 and x_lo in k 16..31).
// ---------------------------------------------------------------------------
#define WH_WORDS (64 * 8 * 64)       // (gu,kt,lane) chunks of 8 bf16
#define WX_WORDS (64 * 64)

__global__ __launch_bounds__(256) void pack_weights(
    const float* __restrict__ wh, const float* __restrict__ wx,
    unsigned short* __restrict__ pb)
{
    int tid = blockIdx.x * 256 + threadIdx.x;
    short8v sv;
    if (tid < WH_WORDS) {
        int lane = tid & 63;
        int kt   = (tid >> 6) & 7;
        int gu   = tid >> 9;
        int g    = gu >> 4;
        int ncol = ((gu & 15) << 4) | (lane & 15);
        int kb   = kt * 32 + ((lane >> 4) << 3);
#pragma unroll
        for (int j = 0; j < 8; ++j)
            sv[j] = (short)f2bf(wh[((size_t)(g * H_ + kb + j)) * H_ + ncol]);
        *(short8v*)(pb + (size_t)tid * 8) = sv;
    } else if (tid < WH_WORDS + WX_WORDS) {
        int t2   = tid - WH_WORDS;
        int lane = t2 & 63;
        int gu   = t2 >> 6;
        int g    = gu >> 4;
        int ncol = ((gu & 15) << 4) | (lane & 15);
        int kkb  = (lane >> 4) << 3;
#pragma unroll
        for (int j = 0; j < 8; ++j) {
            int k = (kkb + j) & 15;   // both K-halves read the same wx rows
            sv[j] = (short)f2bf(wx[((size_t)(g * NX_ + k)) * H_ + ncol]);
        }
        *(short8v*)(pb + (size_t)tid * 8) = sv;
    }
}

// ---------------------------------------------------------------------------
// Persistent LSTM kernel. Block = 16 cells, 8 waves. Wave w owns hidden units
// [w*32, w*32+32) for ALL 4 gates: output tile (g, ut) -> columns
// g*256 + w*32 + ut*16 + (l&15). A-frag (shared by all waves): lane l holds
// A[cell = l&15][k = kt*32 + (l>>4)*8 + j] read as one ds_read_b128 from
// LDS layout A[k>>3][cell][k&7].
// ---------------------------------------------------------------------------
__global__ __launch_bounds__(512) void lstm_mfma(
    const float* __restrict__ x,     // [T][NGRID][NX]
    const float* __restrict__ b,     // [4][H]
    const float* __restrict__ wlin,  // [H]
    const float* __restrict__ blin,  // [1]
    const unsigned short* __restrict__ pb,
    float* __restrict__ out)         // [T][NGRID]
{
    __shared__ __align__(16) unsigned short Ah[2][32][16][8];  // h hi, dbuf
    __shared__ __align__(16) unsigned short Al[2][32][16][8];  // h lo
    __shared__ __align__(16) unsigned short Ax[2][4][16][8];   // x hi|lo K=32
    __shared__ float red[2][8][16];

    const int tid = threadIdx.x;
    const int w   = tid >> 6;
    const int l   = tid & 63;
    const int lg  = l >> 4;     // lane quad -> cells lg*4 .. lg*4+3
    const int ln  = l & 15;
    const int c0  = blockIdx.x * CPB;

    float bias[4][2], wl[2];
#pragma unroll
    for (int g = 0; g < 4; ++g)
#pragma unroll
        for (int ut = 0; ut < 2; ++ut)
            bias[g][ut] = b[g * H_ + w * 32 + ut * 16 + ln];
    wl[0] = wlin[w * 32 + ln];
    wl[1] = wlin[w * 32 + 16 + ln];
    const float bl = blin[0];

    const unsigned short* BX = pb + (size_t)WH_WORDS * 8;

    // h(-1) = 0 in buffer 0
    {
        uint4 z = make_uint4(0, 0, 0, 0);
        ((uint4*)&Ah[0][0][0][0])[tid] = z;   // 512 * 16B = 8 KB
        ((uint4*)&Al[0][0][0][0])[tid] = z;
    }
    // stage x(0) into buffer 0
    if (tid < 256) {
        int cell = tid >> 4, nx = tid & 15;
        float v = x[((size_t)(c0 + cell)) * NX_ + nx];
        unsigned short hi = f2bf(v);
        unsigned short lo = f2bf(v - bf2f(hi));
        Ax[0][nx >> 3][cell][nx & 7] = hi;
        Ax[0][2 + (nx >> 3)][cell][nx & 7] = lo;
    }
    __syncthreads();

    f32x4 acc[4][2];
    float c_st[2][4];
#pragma unroll
    for (int ut = 0; ut < 2; ++ut)
#pragma unroll
        for (int r = 0; r < 4; ++r) c_st[ut][r] = 0.0f;

#pragma unroll 1
    for (int t = 0; t < TSTEPS; ++t) {
        const int rb = t & 1, wb = rb ^ 1;

#pragma unroll
        for (int g = 0; g < 4; ++g)
#pragma unroll
            for (int ut = 0; ut < 2; ++ut) {
                f32x4 a0 = {bias[g][ut], bias[g][ut], bias[g][ut], bias[g][ut]};
                acc[g][ut] = a0;
            }

        // recurrent GEMM: acc += h_hi @ wh + h_lo @ wh
#pragma unroll
        for (int kt = 0; kt < 8; ++kt) {
            short8v ah = *(const short8v*)&Ah[rb][kt * 4 + lg][ln][0];
            short8v al = *(const short8v*)&Al[rb][kt * 4 + lg][ln][0];
#pragma unroll
            for (int g = 0; g < 4; ++g)
#pragma unroll
                for (int ut = 0; ut < 2; ++ut) {
                    int gu = (g << 4) | (w * 2 + ut);
                    short8v bb = *(const short8v*)(pb + ((size_t)(gu * 8 + kt) * 64 + l) * 8);
                    acc[g][ut] = __builtin_amdgcn_mfma_f32_16x16x32_bf16(ah, bb, acc[g][ut], 0, 0, 0);
                    acc[g][ut] = __builtin_amdgcn_mfma_f32_16x16x32_bf16(al, bb, acc[g][ut], 0, 0, 0);
                }
        }
        // input GEMM: acc += [x_hi | x_lo] @ [wx ; wx]   (one K=32 tile)
        {
            short8v axv = *(const short8v*)&Ax[rb][lg][ln][0];
#pragma unroll
            for (int g = 0; g < 4; ++g)
#pragma unroll
                for (int ut = 0; ut < 2; ++ut) {
                    int gu = (g << 4) | (w * 2 + ut);
                    short8v bb = *(const short8v*)(BX + ((size_t)gu * 64 + l) * 8);
                    acc[g][ut] = __builtin_amdgcn_mfma_f32_16x16x32_bf16(axv, bb, acc[g][ut], 0, 0, 0);
                }
        }

        // gates + state update, fully in registers
        float hN[2][4];
#pragma unroll
        for (int ut = 0; ut < 2; ++ut)
#pragma unroll
            for (int r = 0; r < 4; ++r) {
                float ig = sigmoid_f(acc[0][ut][r]);
                float fg = sigmoid_f(acc[1][ut][r]);
                float gt = tanh_f(acc[2][ut][r]);
                float og = sigmoid_f(acc[3][ut][r]);
                float c  = fmaf(fg, c_st[ut][r], ig * gt);
                c_st[ut][r] = c;
                hN[ut][r]   = og * tanh_f(c);
            }

        // publish h(t) (hi/lo) into buffer wb for step t+1
#pragma unroll
        for (int ut = 0; ut < 2; ++ut) {
            int u = w * 32 + ut * 16 + ln;
            int row = u >> 3, q = u & 7;
#pragma unroll
            for (int r = 0; r < 4; ++r) {
                int cell = lg * 4 + r;
                unsigned short hi = f2bf(hN[ut][r]);
                Ah[wb][row][cell][q] = hi;
                Al[wb][row][cell][q] = f2bf(hN[ut][r] - bf2f(hi));
            }
        }
        // stage x(t+1)
        if (t + 1 < TSTEPS && tid < 256) {
            int cell = tid >> 4, nx = tid & 15;
            float v = x[(((size_t)(t + 1)) * NGRID_ + c0 + cell) * NX_ + nx];
            unsigned short hi = f2bf(v);
            unsigned short lo = f2bf(v - bf2f(hi));
            Ax[wb][nx >> 3][cell][nx & 7] = hi;
            Ax[wb][2 + (nx >> 3)][cell][nx & 7] = lo;
        }

        // output head: out[t][cell] = sum_u h*wlin + blin
        {
            float p[4];
#pragma unroll
            for (int r = 0; r < 4; ++r) {
                p[r] = fmaf(hN[0][r], wl[0], hN[1][r] * wl[1]);
#pragma unroll
                for (int off = 1; off < 16; off <<= 1)
                    p[r] += __shfl_xor(p[r], off);
            }
            if (ln == 0) {
#pragma unroll
                for (int r = 0; r < 4; ++r)
                    red[rb][w][lg * 4 + r] = p[r];
            }
        }

        __syncthreads();   // h(t), x(t+1), red visible; all reads of rb done

        if (tid < CPB) {
            float s = bl;
#pragma unroll
            for (int w2 = 0; w2 < 8; ++w2) s += red[rb][w2][tid];
            out[(size_t)t * NGRID_ + c0 + tid] = s;
        }
    }
}

extern "C" void kernel_launch(void* const* d_in, const int* in_sizes, int n_in,
                              void* d_out, int out_size, void* d_ws, size_t ws_size,
                              hipStream_t stream) {
    const float* x    = (const float*)d_in[0];
    const float* wx   = (const float*)d_in[1];
    const float* wh   = (const float*)d_in[2];
    const float* b    = (const float*)d_in[3];
    const float* wlin = (const float*)d_in[4];
    const float* blin = (const float*)d_in[5];
    float* out = (float*)d_out;
    unsigned short* pb = (unsigned short*)d_ws;   // needs 576 KB

    // pack wh+wx into MFMA fragment order (runs every call; ~0.6 MB, trivial)
    hipLaunchKernelGGL(pack_weights, dim3((WH_WORDS + WX_WORDS) / 256), dim3(256),
                       0, stream, wh, wx, pb);
    hipLaunchKernelGGL(lstm_mfma, dim3(NBLK), dim3(512), 0, stream,
                       x, b, wlin, blin, pb, out);
}